// Round 6
// baseline (871.050 us; speedup 1.0000x reference)
//
#include <hip/hip_runtime.h>

// SparseBasicBlock: conv1(gather-GEMM) -> BN+ReLU -> conv2 -> BN -> +residual -> ReLU
// bf16 MFMA 32x32x16 (halves LDS A-read volume vs 16x16x32), fp32 accum.
// Conv: MTILE=64, 256 threads (4 waves = 2 row groups x 2 col groups), 3-buffer
// LDS gather pipeline (2-deep) via global_load_lds (pre-swizzled source, linear
// LDS dest), counted vmcnt + one raw s_barrier per ko, B-fragments in regs.

#define C_CH 128
#define K_OFF 9
#define MTILE 64

typedef __attribute__((ext_vector_type(8))) short bf16x8;
typedef __attribute__((ext_vector_type(16))) float f32x16;
typedef __attribute__((ext_vector_type(8))) unsigned short u16x8;

typedef __attribute__((address_space(1))) const unsigned int* gas_p;
typedef __attribute__((address_space(3))) unsigned int* las_p;

__device__ __forceinline__ void gload_lds16(const unsigned short* g, unsigned short* l) {
    __builtin_amdgcn_global_load_lds((gas_p)g, (las_p)l, 16, 0, 0);
}

__device__ __forceinline__ unsigned short f2b(float f) {
    union { float f; unsigned u; } v; v.f = f;
    unsigned r = v.u + 0x7fffu + ((v.u >> 16) & 1u);   // round-to-nearest-even
    return (unsigned short)(r >> 16);
}
__device__ __forceinline__ float b2f(unsigned short h) {
    union { unsigned u; float f; } v; v.u = ((unsigned)h) << 16;
    return v.f;
}

// ---------------- pre-kernels ----------------

// block 0: zero stats + flags + two zero-sentinel rows; blocks 1..64: detect mask dtype
__global__ void init_detect_k(float* stats, unsigned int* zrow1, unsigned int* zrow2,
                              const unsigned char* __restrict__ m, int* flagA, int* flagB) {
    int t = threadIdx.x;
    if (blockIdx.x == 0) {
        if (t < 256) { stats[t] = 0.f; stats[256 + t] = 0.f; }
        if (t >= 256 && t < 258) ((int*)stats)[1024 + (t - 256)] = 0;  // flagA, flagB
        if (t < 64) { zrow1[t] = 0u; zrow2[t] = 0u; }
    } else {
        int i = (blockIdx.x - 1) * 256 + t;   // first 16KB of mask
        unsigned char v = m[i];
        if ((i & 3) != 0 && v != 0) atomicOr(flagA, 1);
        if (v > 1) atomicOr(flagB, 1);
    }
}

// merged: convert feat->bf16 | pack W1,W2 (32x32 fragment layout) | fold mask+idx -> eidx
// Wp[((ko*4+nt)*8+ks)*512 + lane*8 + j] = W[ko][ks*16+(lane>>5)*8+j][nt*32+(lane&31)]
__global__ void prep_k(const float* __restrict__ x, unsigned short* __restrict__ y, int n4,
                       const float* __restrict__ W1, unsigned short* __restrict__ Wp1,
                       const float* __restrict__ W2, unsigned short* __restrict__ Wp2,
                       const int* __restrict__ nidx, const void* __restrict__ m,
                       const int* __restrict__ flagA, const int* __restrict__ flagB,
                       int* __restrict__ eidx, int NK, int N) {
    const int PACK = K_OFF * 4 * 8 * 512;      // per-tensor packed elements
    int fa = *flagA, fb = *flagB;
    int i = blockIdx.x * blockDim.x + threadIdx.x;
    int s = gridDim.x * blockDim.x;
    int tot = n4 + 2 * PACK + NK;
    for (; i < tot; i += s) {
        if (i < n4) {
            float4 f = ((const float4*)x)[i];
            ushort4 o;
            o.x = f2b(f.x); o.y = f2b(f.y); o.z = f2b(f.z); o.w = f2b(f.w);
            ((ushort4*)y)[i] = o;
        } else if (i < n4 + 2 * PACK) {
            int ii = i - n4;
            const float* W = (ii < PACK) ? W1 : W2;
            unsigned short* Wp = (ii < PACK) ? Wp1 : Wp2;
            if (ii >= PACK) ii -= PACK;
            int j = ii & 7;
            int l = (ii >> 3) & 63;
            int frag = ii >> 9;
            int ks = frag & 7;
            int nt = (frag >> 3) & 3;
            int ko = frag >> 5;
            int cin = ks * 16 + (l >> 5) * 8 + j;
            int cout = nt * 32 + (l & 31);
            Wp[ii] = f2b(W[ko * C_CH * C_CH + cin * C_CH + cout]);
        } else {
            int j = i - n4 - 2 * PACK;
            bool t;
            if (!fa)       t = ((const int*)m)[j] != 0;            // int32
            else if (fb)   t = ((const unsigned*)m)[j] != 0;       // float32 bit test
            else           t = ((const unsigned char*)m)[j] != 0;  // uint8 bool
            eidx[j] = t ? nidx[j] : N;
        }
    }
}

// ---------------- gather-GEMM conv ----------------

__global__ __launch_bounds__(256) void conv_kernel(
    const unsigned short* __restrict__ Xb,   // (N+1) x 128 bf16 (row N = zeros)
    const unsigned short* __restrict__ Wp,   // packed weights (32x32 fragment layout)
    const int* __restrict__ eidx,            // N x 9, masked entries -> N
    unsigned short* __restrict__ Yraw,       // N x 128 bf16 raw conv output
    float* __restrict__ statS, float* __restrict__ statQ)
{
    const int tid = threadIdx.x;
    const int lane = tid & 63;
    const int wv = tid >> 6;          // 0..3
    const int wr = wv >> 1;           // row group 0..1 (32 rows each)
    const int wc = wv & 1;            // col group 0..1 (64 cols each)
    const int tile = blockIdx.x * MTILE;
    const int l31 = lane & 31;
    const int lh = lane >> 5;         // 0..1

    __shared__ alignas(16) unsigned short At[3][MTILE * C_CH]; // 3 x 16KB, linear
    __shared__ int sIdxT[K_OFF][MTILE];                        // 2.25KB

    for (int i = tid; i < MTILE * K_OFF; i += 256) {
        int r = i / K_OFF, k = i - r * K_OFF;
        sIdxT[k][r] = eidx[(size_t)(tile + r) * K_OFF + k];
    }
    __syncthreads();

    const int r_st = tid >> 4;      // 0..15
    const int ch_st = tid & 15;     // 0..15

    // STAGE(buf, ko): 4 async global->LDS 16B loads per thread; LDS dest
    // lane-linear (gload_lds requirement); global source pre-XOR-swizzled
    // (chunk ^ (row&15)) so the swizzled ds_read below recovers the right chunk.
    #define STAGE(buf, ko)                                                        \
        {                                                                         \
            _Pragma("unroll")                                                     \
            for (int jr = 0; jr < 4; ++jr) {                                      \
                int r = jr * 16 + r_st;                                           \
                int g = sIdxT[ko][r];                                             \
                const unsigned short* src =                                       \
                    Xb + (size_t)g * C_CH + ((ch_st ^ (r & 15)) * 8);             \
                unsigned short* dst = &At[buf][r * C_CH + ch_st * 8];             \
                gload_lds16(src, dst);                                            \
            }                                                                     \
        }

    f32x16 acc[2];
    #pragma unroll
    for (int j = 0; j < 2; ++j)
        #pragma unroll
        for (int r = 0; r < 16; ++r) acc[j][r] = 0.f;

    // prologue: stage ko=0 and ko=1 (2-deep)
    STAGE(0, 0);
    STAGE(1, 1);

    // Per iteration KO (fully unrolled):
    //   [B(KO) 16 loads] [sched_barrier] [s_waitcnt vmcnt(VM)] [s_barrier]
    //   [sched_barrier] [STAGE(KO+2)] [8x(ds_read A) + 16 MFMA]
    // VM = #VMEM ops issued after stage(KO):
    //   iter0: s1(4)+B0(16)=20; iters1-7: B(k-1)16+s(k+1)4+B(k)16=36; iter8: B7+B8=32.
    #define CONV_ITER(KO, VM)                                                     \
        {                                                                         \
            bf16x8 bfrag0[8], bfrag1[8];                                          \
            const unsigned short* wb = Wp + (size_t)(KO) * (4 * 8 * 512) + lane * 8; \
            _Pragma("unroll")                                                     \
            for (int ks = 0; ks < 8; ++ks) {                                      \
                bfrag0[ks] = *(const bf16x8*)(wb + ((wc * 2 + 0) * 8 + ks) * 512);\
                bfrag1[ks] = *(const bf16x8*)(wb + ((wc * 2 + 1) * 8 + ks) * 512);\
            }                                                                     \
            __builtin_amdgcn_sched_barrier(0);                                    \
            asm volatile("s_waitcnt vmcnt(" #VM ")" ::: "memory");                \
            __builtin_amdgcn_s_barrier();                                         \
            __builtin_amdgcn_sched_barrier(0);                                    \
            if ((KO) + 2 < K_OFF) { STAGE((((KO) + 2) % 3), (KO) + 2); }          \
            __builtin_amdgcn_s_setprio(1);                                        \
            {                                                                     \
                const int row = wr * 32 + l31;                                    \
                bf16x8 a[8];                                                      \
                _Pragma("unroll")                                                 \
                for (int ks = 0; ks < 8; ++ks) {                                  \
                    int sc = (ks * 2 + lh) ^ (row & 15);                          \
                    a[ks] = *(const bf16x8*)((const char*)At[(KO) % 3] + row * 256 + sc * 16); \
                }                                                                 \
                _Pragma("unroll")                                                 \
                for (int ks = 0; ks < 8; ++ks) {                                  \
                    acc[0] = __builtin_amdgcn_mfma_f32_32x32x16_bf16(a[ks], bfrag0[ks], acc[0], 0, 0, 0); \
                    acc[1] = __builtin_amdgcn_mfma_f32_32x32x16_bf16(a[ks], bfrag1[ks], acc[1], 0, 0, 0); \
                }                                                                 \
            }                                                                     \
            __builtin_amdgcn_s_setprio(0);                                        \
        }

    CONV_ITER(0, 20)
    CONV_ITER(1, 36)
    CONV_ITER(2, 36)
    CONV_ITER(3, 36)
    CONV_ITER(4, 36)
    CONV_ITER(5, 36)
    CONV_ITER(6, 36)
    CONV_ITER(7, 36)
    CONV_ITER(8, 32)
    #undef CONV_ITER
    #undef STAGE

    // ---- per-channel stats: lane&31 owns col (wc*2+jn)*32 + l31 ----
    // rows covered per lane: 16 of this wave's 32; lane^32 covers the other 16.
    #pragma unroll
    for (int jn = 0; jn < 2; ++jn) {
        float s = 0.f, q = 0.f;
        #pragma unroll
        for (int r = 0; r < 16; ++r) { float v = acc[jn][r]; s += v; q += v * v; }
        s += __shfl_xor(s, 32);
        q += __shfl_xor(q, 32);
        if (lane < 32) {
            int col = (wc * 2 + jn) * 32 + l31;
            atomicAdd(&statS[col], s);
            atomicAdd(&statQ[col], q);
        }
    }

    // ---- write raw conv output (bf16); C/D: col=lane&31, row=(r&3)+8*(r>>2)+4*lh ----
    #pragma unroll
    for (int jn = 0; jn < 2; ++jn) {
        int col = (wc * 2 + jn) * 32 + l31;
        #pragma unroll
        for (int r = 0; r < 16; ++r) {
            int row = tile + wr * 32 + (r & 3) + 8 * (r >> 2) + 4 * lh;
            Yraw[(size_t)row * C_CH + col] = f2b(acc[jn][r]);
        }
    }
}

// ---------------- BN finalize / apply ----------------

__global__ void finalize_bn_k(const float* __restrict__ S, const float* __restrict__ Q,
                              const float* __restrict__ gamma, const float* __restrict__ beta,
                              float* __restrict__ scale, float* __restrict__ bias, float invN) {
    int c = threadIdx.x;
    if (c < C_CH) {
        float mu = S[c] * invN;
        float var = Q[c] * invN - mu * mu;
        float inv = rsqrtf(var + 1e-4f);
        float sc = gamma[c] * inv;
        scale[c] = sc;
        bias[c] = beta[c] - mu * sc;
    }
}

__global__ void bn_relu_k(unsigned short* __restrict__ y,
                          const float* __restrict__ scale, const float* __restrict__ bias, int n8) {
    int i0 = blockIdx.x * blockDim.x + threadIdx.x;
    int S = gridDim.x * blockDim.x;
    int c0 = (i0 * 8) & (C_CH - 1);
    float sc[8], bs[8];
    #pragma unroll
    for (int j = 0; j < 8; ++j) { sc[j] = scale[c0 + j]; bs[j] = bias[c0 + j]; }
    for (int i = i0; i < n8; i += S) {
        u16x8 v = ((const u16x8*)y)[i];
        #pragma unroll
        for (int j = 0; j < 8; ++j) {
            float x = b2f((unsigned short)v[j]);
            x = fmaxf(x * sc[j] + bs[j], 0.f);
            v[j] = (short)f2b(x);
        }
        ((u16x8*)y)[i] = v;
    }
}

__global__ void final_fuse_k(const unsigned short* __restrict__ raw,
                             const float* __restrict__ feat,
                             const float* __restrict__ scale, const float* __restrict__ bias,
                             float* __restrict__ out, int n4) {
    int i0 = blockIdx.x * blockDim.x + threadIdx.x;
    int S = gridDim.x * blockDim.x;
    int c0 = (i0 * 4) & (C_CH - 1);
    float sc[4], bs[4];
    #pragma unroll
    for (int j = 0; j < 4; ++j) { sc[j] = scale[c0 + j]; bs[j] = bias[c0 + j]; }
    for (int i = i0; i < n4; i += S) {
        ushort4 r = ((const ushort4*)raw)[i];
        float4 f = ((const float4*)feat)[i];
        float4 o;
        o.x = fmaxf(b2f(r.x) * sc[0] + bs[0] + f.x, 0.f);
        o.y = fmaxf(b2f(r.y) * sc[1] + bs[1] + f.y, 0.f);
        o.z = fmaxf(b2f(r.z) * sc[2] + bs[2] + f.z, 0.f);
        o.w = fmaxf(b2f(r.w) * sc[3] + bs[3] + f.w, 0.f);
        ((float4*)out)[i] = o;
    }
}

// ---------------- launch ----------------

extern "C" void kernel_launch(void* const* d_in, const int* in_sizes, int n_in,
                              void* d_out, int out_size, void* d_ws, size_t ws_size,
                              hipStream_t stream) {
    const float* feat = (const float*)d_in[0];
    const float* W1 = (const float*)d_in[1];
    const float* W2 = (const float*)d_in[2];
    const float* g1 = (const float*)d_in[3];
    const float* b1 = (const float*)d_in[4];
    const float* g2 = (const float*)d_in[5];
    const float* b2 = (const float*)d_in[6];
    const int* nidx = (const int*)d_in[7];
    const void* nmask = d_in[8];

    const int N = in_sizes[0] / C_CH;   // 400000
    const int NK = N * K_OFF;

    char* ws = (char*)d_ws;
    unsigned short* featb = (unsigned short*)ws;                          // (N+1) x 128 bf16
    size_t off = (size_t)(N + 1) * C_CH * 2;
    off = (off + 255) & ~(size_t)255;
    unsigned short* Wp1 = (unsigned short*)(ws + off); off += (size_t)K_OFF * C_CH * C_CH * 2;
    unsigned short* Wp2 = (unsigned short*)(ws + off); off += (size_t)K_OFF * C_CH * C_CH * 2;
    float* stats = (float*)(ws + off);
    float* S1 = stats;        float* Q1 = stats + 128;
    float* S2 = stats + 256;  float* Q2 = stats + 384;
    float* sc1 = stats + 512; float* bi1 = stats + 640;
    float* sc2 = stats + 768; float* bi2 = stats + 896;
    int* flagA = ((int*)stats) + 1024;
    int* flagB = ((int*)stats) + 1025;

    // scratch inside d_out: y1 = rows [0, N] bf16 (~102.4MB); eidx at +128MiB.
    unsigned short* y1 = (unsigned short*)d_out;
    int* eidx = (int*)((char*)d_out + (size_t)134217728);
    unsigned short* out2raw = featb;               // reuse feat-bf16 region after conv1

    hipLaunchKernelGGL(init_detect_k, dim3(65), dim3(256), 0, stream,
                       stats, (unsigned int*)(featb + (size_t)N * C_CH),
                       (unsigned int*)(y1 + (size_t)N * C_CH),
                       (const unsigned char*)nmask, flagA, flagB);
    hipLaunchKernelGGL(prep_k, dim3(2048), dim3(256), 0, stream,
                       feat, featb, N * C_CH / 4,
                       W1, Wp1, W2, Wp2,
                       nidx, nmask, flagA, flagB, eidx, NK, N);

    hipLaunchKernelGGL(conv_kernel, dim3(N / MTILE), dim3(256), 0, stream,
                       featb, Wp1, eidx, y1, S1, Q1);
    hipLaunchKernelGGL(finalize_bn_k, dim3(1), dim3(128), 0, stream, S1, Q1, g1, b1, sc1, bi1, 1.0f / N);
    hipLaunchKernelGGL(bn_relu_k, dim3(2048), dim3(256), 0, stream, y1, sc1, bi1, N * C_CH / 8);

    hipLaunchKernelGGL(conv_kernel, dim3(N / MTILE), dim3(256), 0, stream,
                       y1, Wp2, eidx, out2raw, S2, Q2);
    hipLaunchKernelGGL(finalize_bn_k, dim3(1), dim3(128), 0, stream, S2, Q2, g2, b2, sc2, bi2, 1.0f / N);
    hipLaunchKernelGGL(final_fuse_k, dim3(2048), dim3(256), 0, stream,
                       out2raw, feat, sc2, bi2, (float*)d_out, N * C_CH / 4);
}

// Round 7
// 565.528 us; speedup vs baseline: 1.5402x; 1.5402x over previous
//
#include <hip/hip_runtime.h>

// SparseBasicBlock: conv1(gather-GEMM) -> BN+ReLU -> conv2 -> BN -> +residual -> ReLU
// bf16 MFMA 16x16x32, fp32 accum. Conv: MTILE=64, 4 waves (col-split), 3-buffer
// LDS gather pipeline (2-deep) via global_load_lds + register-double-buffered
// B-fragments (1-deep), uniform counted vmcnt(12) + one raw s_barrier per ko.

#define C_CH 128
#define K_OFF 9
#define MTILE 64

typedef __attribute__((ext_vector_type(8))) short bf16x8;
typedef __attribute__((ext_vector_type(4))) float f32x4;
typedef __attribute__((ext_vector_type(8))) unsigned short u16x8;

typedef __attribute__((address_space(1))) const unsigned int* gas_p;
typedef __attribute__((address_space(3))) unsigned int* las_p;

__device__ __forceinline__ void gload_lds16(const unsigned short* g, unsigned short* l) {
    __builtin_amdgcn_global_load_lds((gas_p)g, (las_p)l, 16, 0, 0);
}

__device__ __forceinline__ unsigned short f2b(float f) {
    union { float f; unsigned u; } v; v.f = f;
    unsigned r = v.u + 0x7fffu + ((v.u >> 16) & 1u);   // round-to-nearest-even
    return (unsigned short)(r >> 16);
}
__device__ __forceinline__ float b2f(unsigned short h) {
    union { unsigned u; float f; } v; v.u = ((unsigned)h) << 16;
    return v.f;
}

// ---------------- pre-kernels ----------------

// block 0: zero stats + flags + two zero-sentinel rows; blocks 1..64: detect mask dtype
__global__ void init_detect_k(float* stats, unsigned int* zrow1, unsigned int* zrow2,
                              const unsigned char* __restrict__ m, int* flagA, int* flagB) {
    int t = threadIdx.x;
    if (blockIdx.x == 0) {
        if (t < 256) { stats[t] = 0.f; stats[256 + t] = 0.f; }
        if (t >= 256 && t < 258) ((int*)stats)[1024 + (t - 256)] = 0;  // flagA, flagB
        if (t < 64) { zrow1[t] = 0u; zrow2[t] = 0u; }
    } else {
        int i = (blockIdx.x - 1) * 256 + t;   // first 16KB of mask
        unsigned char v = m[i];
        if ((i & 3) != 0 && v != 0) atomicOr(flagA, 1);
        if (v > 1) atomicOr(flagB, 1);
    }
}

// merged: convert feat->bf16 | pack W1,W2 (16x16 B-fragment layout) | fold mask+idx -> eidx
// Wp[((ko*8+nt)*4+ks)*512 + lane*8 + j] = W[ko][ks*32+(lane>>4)*8+j][nt*16+(lane&15)]
__global__ void prep_k(const float* __restrict__ x, unsigned short* __restrict__ y, int n4,
                       const float* __restrict__ W1, unsigned short* __restrict__ Wp1,
                       const float* __restrict__ W2, unsigned short* __restrict__ Wp2,
                       const int* __restrict__ nidx, const void* __restrict__ m,
                       const int* __restrict__ flagA, const int* __restrict__ flagB,
                       int* __restrict__ eidx, int NK, int N) {
    const int PACK = K_OFF * 8 * 4 * 512;      // per-tensor packed elements
    int fa = *flagA, fb = *flagB;
    int i = blockIdx.x * blockDim.x + threadIdx.x;
    int s = gridDim.x * blockDim.x;
    int tot = n4 + 2 * PACK + NK;
    for (; i < tot; i += s) {
        if (i < n4) {
            float4 f = ((const float4*)x)[i];
            ushort4 o;
            o.x = f2b(f.x); o.y = f2b(f.y); o.z = f2b(f.z); o.w = f2b(f.w);
            ((ushort4*)y)[i] = o;
        } else if (i < n4 + 2 * PACK) {
            int ii = i - n4;
            const float* W = (ii < PACK) ? W1 : W2;
            unsigned short* Wp = (ii < PACK) ? Wp1 : Wp2;
            if (ii >= PACK) ii -= PACK;
            int j = ii & 7;
            int l = (ii >> 3) & 63;
            int frag = ii >> 9;
            int ks = frag & 3;
            int nt = (frag >> 2) & 7;
            int ko = frag >> 5;
            int cin = ks * 32 + (l >> 4) * 8 + j;
            int cout = nt * 16 + (l & 15);
            Wp[ii] = f2b(W[ko * C_CH * C_CH + cin * C_CH + cout]);
        } else {
            int j = i - n4 - 2 * PACK;
            bool t;
            if (!fa)       t = ((const int*)m)[j] != 0;            // int32
            else if (fb)   t = ((const unsigned*)m)[j] != 0;       // float32 bit test
            else           t = ((const unsigned char*)m)[j] != 0;  // uint8 bool
            eidx[j] = t ? nidx[j] : N;
        }
    }
}

// ---------------- gather-GEMM conv ----------------

__global__ __launch_bounds__(256, 3) void conv_kernel(
    const unsigned short* __restrict__ Xb,   // (N+1) x 128 bf16 (row N = zeros)
    const unsigned short* __restrict__ Wp,   // packed weights (fragment layout)
    const int* __restrict__ eidx,            // N x 9, masked entries -> N
    unsigned short* __restrict__ Yraw,       // N x 128 bf16 raw conv output
    float* __restrict__ statS, float* __restrict__ statQ)
{
    const int tid = threadIdx.x;
    const int lane = tid & 63;
    const int wv = tid >> 6;          // wave 0..3 owns cols [wv*32, wv*32+32)
    const int tile = blockIdx.x * MTILE;
    const int asub = lane >> 4;       // 0..3
    const int l15 = lane & 15;

    __shared__ alignas(16) unsigned short At[3][MTILE * C_CH]; // 3 x 16KB, linear
    __shared__ int sIdxT[K_OFF][MTILE];                        // 2.25KB

    for (int i = tid; i < MTILE * K_OFF; i += 256) {
        int r = i / K_OFF, k = i - r * K_OFF;
        sIdxT[k][r] = eidx[(size_t)(tile + r) * K_OFF + k];
    }
    __syncthreads();

    const int r_st = tid >> 4;      // 0..15
    const int ch_st = tid & 15;     // 0..15

    // STAGE(buf, ko): 4 async global->LDS 16B loads; LDS dest lane-linear
    // (gload_lds requirement); global source pre-XOR-swizzled so the swizzled
    // ds_read below recovers the right chunk.
    #define STAGE(buf, ko)                                                        \
        {                                                                         \
            _Pragma("unroll")                                                     \
            for (int jr = 0; jr < 4; ++jr) {                                      \
                int r = jr * 16 + r_st;                                           \
                int g = sIdxT[ko][r];                                             \
                const unsigned short* src =                                       \
                    Xb + (size_t)g * C_CH + ((ch_st ^ (r & 7)) * 8);              \
                unsigned short* dst = &At[buf][r * C_CH + ch_st * 8];             \
                gload_lds16(src, dst);                                            \
            }                                                                     \
        }

    // LOADB*(ko): 8 x 16B global loads of this wave's 2 col-tiles into named regs
    #define LOADB0(ko)                                                            \
        {                                                                         \
            const unsigned short* wb = Wp + (size_t)(ko) * (8 * 4 * 512) + lane * 8; \
            _Pragma("unroll")                                                     \
            for (int ks = 0; ks < 4; ++ks) {                                      \
                b0a[ks] = *(const bf16x8*)(wb + ((wv * 2 + 0) * 4 + ks) * 512);   \
                b0b[ks] = *(const bf16x8*)(wb + ((wv * 2 + 1) * 4 + ks) * 512);   \
            }                                                                     \
        }
    #define LOADB1(ko)                                                            \
        {                                                                         \
            const unsigned short* wb = Wp + (size_t)(ko) * (8 * 4 * 512) + lane * 8; \
            _Pragma("unroll")                                                     \
            for (int ks = 0; ks < 4; ++ks) {                                      \
                b1a[ks] = *(const bf16x8*)(wb + ((wv * 2 + 0) * 4 + ks) * 512);   \
                b1b[ks] = *(const bf16x8*)(wb + ((wv * 2 + 1) * 4 + ks) * 512);   \
            }                                                                     \
        }

    f32x4 acc[4][2];
    #pragma unroll
    for (int m = 0; m < 4; ++m) { acc[m][0] = (f32x4){0,0,0,0}; acc[m][1] = (f32x4){0,0,0,0}; }

    bf16x8 b0a[4], b0b[4], b1a[4], b1b[4];

    // prologue: queue order = s0(4) B0(8) s1(4)  [then B1(8) at iter 0]
    STAGE(0, 0);
    LOADB0(0);
    STAGE(1, 1);

    // Per iteration KO (fully unrolled):
    //   [LOADB(KO+1) -> other parity regs] [sched_barrier]
    //   [s_waitcnt vmcnt(VM)] [s_barrier] [sched_barrier]
    //   [STAGE(KO+2)] [setprio(1): 16x ds_read A + 32 MFMA]
    // Queue at the wait: s(KO) B(KO) | s(KO+1) B(KO+1)  -> wait B(KO) done:
    // VM = 12 (leaves s(KO+1)+B(KO+1)); last iter drains (VM=0).
    #define CONV_ITER(KO, BA, BB, LB, VM)                                         \
        {                                                                         \
            if ((KO) + 1 < K_OFF) { LB((KO) + 1); }                               \
            __builtin_amdgcn_sched_barrier(0);                                    \
            asm volatile("s_waitcnt vmcnt(" #VM ")" ::: "memory");                \
            __builtin_amdgcn_s_barrier();                                         \
            __builtin_amdgcn_sched_barrier(0);                                    \
            if ((KO) + 2 < K_OFF) { STAGE((((KO) + 2) % 3), (KO) + 2); }          \
            __builtin_amdgcn_s_setprio(1);                                        \
            _Pragma("unroll")                                                     \
            for (int m = 0; m < 4; ++m) {                                         \
                bf16x8 a[4];                                                      \
                _Pragma("unroll")                                                 \
                for (int ks = 0; ks < 4; ++ks) {                                  \
                    int row = m * 16 + l15;                                       \
                    int sc = (ks * 4 + asub) ^ (row & 7);                         \
                    a[ks] = *(const bf16x8*)((const char*)At[(KO) % 3] + row * 256 + sc * 16); \
                }                                                                 \
                _Pragma("unroll")                                                 \
                for (int ks = 0; ks < 4; ++ks) {                                  \
                    acc[m][0] = __builtin_amdgcn_mfma_f32_16x16x32_bf16(a[ks], BA[ks], acc[m][0], 0, 0, 0); \
                    acc[m][1] = __builtin_amdgcn_mfma_f32_16x16x32_bf16(a[ks], BB[ks], acc[m][1], 0, 0, 0); \
                }                                                                 \
            }                                                                     \
            __builtin_amdgcn_s_setprio(0);                                        \
        }

    CONV_ITER(0, b0a, b0b, LOADB1, 12)
    CONV_ITER(1, b1a, b1b, LOADB0, 12)
    CONV_ITER(2, b0a, b0b, LOADB1, 12)
    CONV_ITER(3, b1a, b1b, LOADB0, 12)
    CONV_ITER(4, b0a, b0b, LOADB1, 12)
    CONV_ITER(5, b1a, b1b, LOADB0, 12)
    CONV_ITER(6, b0a, b0b, LOADB1, 12)
    CONV_ITER(7, b1a, b1b, LOADB0, 12)
    CONV_ITER(8, b0a, b0b, LOADB1, 0)
    #undef CONV_ITER
    #undef STAGE
    #undef LOADB0
    #undef LOADB1

    // ---- per-channel stats (each wave owns channels [wv*32, wv*32+32)) ----
    #pragma unroll
    for (int j = 0; j < 2; ++j) {
        float s = 0.f, q = 0.f;
        #pragma unroll
        for (int m = 0; m < 4; ++m)
            #pragma unroll
            for (int r = 0; r < 4; ++r) { float v = acc[m][j][r]; s += v; q += v * v; }
        s += __shfl_xor(s, 16); s += __shfl_xor(s, 32);
        q += __shfl_xor(q, 16); q += __shfl_xor(q, 32);
        if (lane < 16) {
            atomicAdd(&statS[wv * 32 + j * 16 + lane], s);
            atomicAdd(&statQ[wv * 32 + j * 16 + lane], q);
        }
    }

    // ---- write raw conv output (bf16) ----
    #pragma unroll
    for (int m = 0; m < 4; ++m)
        #pragma unroll
        for (int j = 0; j < 2; ++j) {
            int col = (wv * 2 + j) * 16 + l15;
            #pragma unroll
            for (int r = 0; r < 4; ++r) {
                int row = tile + m * 16 + asub * 4 + r;
                Yraw[(size_t)row * C_CH + col] = f2b(acc[m][j][r]);
            }
        }
}

// ---------------- BN finalize / apply ----------------

__global__ void finalize_bn_k(const float* __restrict__ S, const float* __restrict__ Q,
                              const float* __restrict__ gamma, const float* __restrict__ beta,
                              float* __restrict__ scale, float* __restrict__ bias, float invN) {
    int c = threadIdx.x;
    if (c < C_CH) {
        float mu = S[c] * invN;
        float var = Q[c] * invN - mu * mu;
        float inv = rsqrtf(var + 1e-4f);
        float sc = gamma[c] * inv;
        scale[c] = sc;
        bias[c] = beta[c] - mu * sc;
    }
}

__global__ void bn_relu_k(unsigned short* __restrict__ y,
                          const float* __restrict__ scale, const float* __restrict__ bias, int n8) {
    int i0 = blockIdx.x * blockDim.x + threadIdx.x;
    int S = gridDim.x * blockDim.x;
    int c0 = (i0 * 8) & (C_CH - 1);
    float sc[8], bs[8];
    #pragma unroll
    for (int j = 0; j < 8; ++j) { sc[j] = scale[c0 + j]; bs[j] = bias[c0 + j]; }
    for (int i = i0; i < n8; i += S) {
        u16x8 v = ((const u16x8*)y)[i];
        #pragma unroll
        for (int j = 0; j < 8; ++j) {
            float x = b2f((unsigned short)v[j]);
            x = fmaxf(x * sc[j] + bs[j], 0.f);
            v[j] = (short)f2b(x);
        }
        ((u16x8*)y)[i] = v;
    }
}

__global__ void final_fuse_k(const unsigned short* __restrict__ raw,
                             const float* __restrict__ feat,
                             const float* __restrict__ scale, const float* __restrict__ bias,
                             float* __restrict__ out, int n4) {
    int i0 = blockIdx.x * blockDim.x + threadIdx.x;
    int S = gridDim.x * blockDim.x;
    int c0 = (i0 * 4) & (C_CH - 1);
    float sc[4], bs[4];
    #pragma unroll
    for (int j = 0; j < 4; ++j) { sc[j] = scale[c0 + j]; bs[j] = bias[c0 + j]; }
    for (int i = i0; i < n4; i += S) {
        ushort4 r = ((const ushort4*)raw)[i];
        float4 f = ((const float4*)feat)[i];
        float4 o;
        o.x = fmaxf(b2f(r.x) * sc[0] + bs[0] + f.x, 0.f);
        o.y = fmaxf(b2f(r.y) * sc[1] + bs[1] + f.y, 0.f);
        o.z = fmaxf(b2f(r.z) * sc[2] + bs[2] + f.z, 0.f);
        o.w = fmaxf(b2f(r.w) * sc[3] + bs[3] + f.w, 0.f);
        ((float4*)out)[i] = o;
    }
}

// ---------------- launch ----------------

extern "C" void kernel_launch(void* const* d_in, const int* in_sizes, int n_in,
                              void* d_out, int out_size, void* d_ws, size_t ws_size,
                              hipStream_t stream) {
    const float* feat = (const float*)d_in[0];
    const float* W1 = (const float*)d_in[1];
    const float* W2 = (const float*)d_in[2];
    const float* g1 = (const float*)d_in[3];
    const float* b1 = (const float*)d_in[4];
    const float* g2 = (const float*)d_in[5];
    const float* b2 = (const float*)d_in[6];
    const int* nidx = (const int*)d_in[7];
    const void* nmask = d_in[8];

    const int N = in_sizes[0] / C_CH;   // 400000
    const int NK = N * K_OFF;

    char* ws = (char*)d_ws;
    unsigned short* featb = (unsigned short*)ws;                          // (N+1) x 128 bf16
    size_t off = (size_t)(N + 1) * C_CH * 2;
    off = (off + 255) & ~(size_t)255;
    unsigned short* Wp1 = (unsigned short*)(ws + off); off += (size_t)K_OFF * C_CH * C_CH * 2;
    unsigned short* Wp2 = (unsigned short*)(ws + off); off += (size_t)K_OFF * C_CH * C_CH * 2;
    float* stats = (float*)(ws + off);
    float* S1 = stats;        float* Q1 = stats + 128;
    float* S2 = stats + 256;  float* Q2 = stats + 384;
    float* sc1 = stats + 512; float* bi1 = stats + 640;
    float* sc2 = stats + 768; float* bi2 = stats + 896;
    int* flagA = ((int*)stats) + 1024;
    int* flagB = ((int*)stats) + 1025;

    // scratch inside d_out: y1 = rows [0, N] bf16 (~102.4MB); eidx at +128MiB.
    unsigned short* y1 = (unsigned short*)d_out;
    int* eidx = (int*)((char*)d_out + (size_t)134217728);
    unsigned short* out2raw = featb;               // reuse feat-bf16 region after conv1

    hipLaunchKernelGGL(init_detect_k, dim3(65), dim3(256), 0, stream,
                       stats, (unsigned int*)(featb + (size_t)N * C_CH),
                       (unsigned int*)(y1 + (size_t)N * C_CH),
                       (const unsigned char*)nmask, flagA, flagB);
    hipLaunchKernelGGL(prep_k, dim3(2048), dim3(256), 0, stream,
                       feat, featb, N * C_CH / 4,
                       W1, Wp1, W2, Wp2,
                       nidx, nmask, flagA, flagB, eidx, NK, N);

    hipLaunchKernelGGL(conv_kernel, dim3(N / MTILE), dim3(256), 0, stream,
                       featb, Wp1, eidx, y1, S1, Q1);
    hipLaunchKernelGGL(finalize_bn_k, dim3(1), dim3(128), 0, stream, S1, Q1, g1, b1, sc1, bi1, 1.0f / N);
    hipLaunchKernelGGL(bn_relu_k, dim3(2048), dim3(256), 0, stream, y1, sc1, bi1, N * C_CH / 8);

    hipLaunchKernelGGL(conv_kernel, dim3(N / MTILE), dim3(256), 0, stream,
                       y1, Wp2, eidx, out2raw, S2, Q2);
    hipLaunchKernelGGL(finalize_bn_k, dim3(1), dim3(128), 0, stream, S2, Q2, g2, b2, sc2, bi2, 1.0f / N);
    hipLaunchKernelGGL(final_fuse_k, dim3(2048), dim3(256), 0, stream,
                       out2raw, feat, sc2, bi2, (float*)d_out, N * C_CH / 4);
}